// Round 4
// baseline (1487.397 us; speedup 1.0000x reference)
//
#include <hip/hip_runtime.h>

// LSTM: B=512, T=1024, D=64, H=128, gates=4H=512, fc head H->64->1.
// 256 blocks (1/CU) x 1024 threads (16 waves = 4/SIMD), 2 batch rows/block.
// Thread t: q = t&3 (K-quarter), g = t>>2 (gate group) owns gates {g, g+256}
// with f16 weights for K-slice [48q, 48q+48) of the concatenated [h|x] vector
// (K = 128+64 = 192): 2 x 24 half2 = 48 weight VGPRs -> register-resident
// (round 1-3: compiler refused 96-192-VGPR weight arrays and re-streamed
// from L2 every step). Gate math: v_dot2_f32_f16 via INLINE ASM -- round 3's
// __builtin_amdgcn_fdot2 guard silently fell back to cvt+fma (~2.4x VALU).
// Partial sums combined with shfl_xor over the 4-lane K-group. fp32 c-state.

#define BB 512
#define TT 1024
#define DD 64
#define HH 128
#define KK 192   // h(128) | x(64)

typedef _Float16 half2_t __attribute__((ext_vector_type(2)));

__device__ __forceinline__ float dot2(half2_t a, half2_t b, float c) {
    asm("v_dot2_f32_f16 %0, %1, %2, %0" : "+v"(c) : "v"(a), "v"(b));
    return c;
}

__device__ __forceinline__ half2_t pack2(float a, float b) {
    half2_t r;
    r[0] = (_Float16)a;
    r[1] = (_Float16)b;
    return r;
}

__device__ __forceinline__ half2_t bc(unsigned int u) {
    return __builtin_bit_cast(half2_t, u);
}

__device__ __forceinline__ float sigm(float x) {
    return 1.f / (1.f + __expf(-x));
}
__device__ __forceinline__ float tanh_f(float x) {
    return 1.f - 2.f / (__expf(2.f * x) + 1.f);
}

// weight element for gate row, concatenated index k: [W_hh row | W_ih row]
__device__ __forceinline__ half2_t wld(const float* __restrict__ Whh,
                                       const float* __restrict__ Wih,
                                       int gate, int k) {
    // k is even and the h/x boundary (128) is even: k,k+1 never straddle
    if (k < HH) return pack2(Whh[gate * HH + k], Whh[gate * HH + k + 1]);
    return pack2(Wih[gate * DD + (k - HH)], Wih[gate * DD + (k - HH) + 1]);
}

__global__ __launch_bounds__(1024, 4)
void lstm_fused_kernel(const float* __restrict__ x_seq,
                       const float* __restrict__ W_ih,
                       const float* __restrict__ W_hh,
                       const float* __restrict__ b_ih,
                       const float* __restrict__ b_hh,
                       const float* __restrict__ W1v,
                       const float* __restrict__ b1v,
                       const float* __restrict__ W2v,
                       const float* __restrict__ b2v,
                       float* __restrict__ out)
{
    const int tid = threadIdx.x;
    const int q   = tid & 3;        // K-quarter
    const int g   = tid >> 2;       // gate group: gates g and g+256
    const int b0  = blockIdx.x * 2;

    __shared__ __align__(16) _Float16 hx[2][2][KK];  // [buf][row][h|x] f16
    __shared__ __align__(16) float    gl[2][4 * HH]; // [row][gate] f32

    // ---- per-thread weights: 24 half2 per gate (48 VGPRs total) ----
    const int k0 = q * 48;
    half2_t wa[24], wb[24];
#pragma unroll
    for (int j = 0; j < 24; ++j) {
        wa[j] = wld(W_hh, W_ih, g,       k0 + 2 * j);
        wb[j] = wld(W_hh, W_ih, g + 256, k0 + 2 * j);
    }
    const float biasA = b_ih[g] + b_hh[g];
    const float biasB = b_ih[g + 256] + b_hh[g + 256];

    // ---- init: h=0 and x(0) into buffer 0 ----
    if (tid < 256) hx[0][tid >> 7][tid & 127] = (_Float16)0.f;
    if (tid < 128) {
        const int r = tid >> 6, k = tid & 63;
        hx[0][r][HH + k] = (_Float16)x_seq[((b0 + r) * TT + 0) * DD + k];
    }
    float c_reg = 0.f;                       // owned by threads < 256
    const int pr = (tid - 896) >> 6;         // x-prefetch coords (tid>=896)
    const int pk = (tid - 896) & 63;
    __syncthreads();

    for (int t = 0; t < TT; ++t) {
        const int cur = t & 1;

        // issue next-x load early (waves 14-15); latency hides under dot2s
        float xpre = 0.f;
        const bool do_pre = (t + 1 < TT) && (tid >= 896);
        if (do_pre) xpre = x_seq[((b0 + pr) * TT + (t + 1)) * DD + pk];

        // ---- gate phase: 12 ds_read_b128 + 96 v_dot2_f32_f16 ----
        const uint4* s0 = reinterpret_cast<const uint4*>(&hx[cur][0][k0]);
        const uint4* s1 = reinterpret_cast<const uint4*>(&hx[cur][1][k0]);
        float aA0 = 0.f, aA1 = 0.f, aB0 = 0.f, aB1 = 0.f;
#pragma unroll
        for (int j = 0; j < 6; ++j) {
            const uint4 v0 = s0[j];
            const uint4 v1 = s1[j];
            aA0 = dot2(wa[4 * j + 0], bc(v0.x), aA0);
            aA1 = dot2(wa[4 * j + 0], bc(v1.x), aA1);
            aB0 = dot2(wb[4 * j + 0], bc(v0.x), aB0);
            aB1 = dot2(wb[4 * j + 0], bc(v1.x), aB1);
            aA0 = dot2(wa[4 * j + 1], bc(v0.y), aA0);
            aA1 = dot2(wa[4 * j + 1], bc(v1.y), aA1);
            aB0 = dot2(wb[4 * j + 1], bc(v0.y), aB0);
            aB1 = dot2(wb[4 * j + 1], bc(v1.y), aB1);
            aA0 = dot2(wa[4 * j + 2], bc(v0.z), aA0);
            aA1 = dot2(wa[4 * j + 2], bc(v1.z), aA1);
            aB0 = dot2(wb[4 * j + 2], bc(v0.z), aB0);
            aB1 = dot2(wb[4 * j + 2], bc(v1.z), aB1);
            aA0 = dot2(wa[4 * j + 3], bc(v0.w), aA0);
            aA1 = dot2(wa[4 * j + 3], bc(v1.w), aA1);
            aB0 = dot2(wb[4 * j + 3], bc(v0.w), aB0);
            aB1 = dot2(wb[4 * j + 3], bc(v1.w), aB1);
        }

        // ---- combine K-quarters across the 4-lane group ----
        aA0 += __shfl_xor(aA0, 1, 64); aA0 += __shfl_xor(aA0, 2, 64);
        aA1 += __shfl_xor(aA1, 1, 64); aA1 += __shfl_xor(aA1, 2, 64);
        aB0 += __shfl_xor(aB0, 1, 64); aB0 += __shfl_xor(aB0, 2, 64);
        aB1 += __shfl_xor(aB1, 1, 64); aB1 += __shfl_xor(aB1, 2, 64);

        // lane q writes result q: {(r0,g),(r1,g),(r0,g+256),(r1,g+256)}
        const float v  = (q == 0) ? aA0 : (q == 1) ? aA1 : (q == 2) ? aB0 : aB1;
        const float bb = (q < 2) ? biasA : biasB;
        const int   row = q & 1;
        const int   gg  = (q < 2) ? g : g + 256;
        gl[row][gg] = v + bb;
        __syncthreads();

        // ---- cell phase (waves 0-3) + x-prefetch write (waves 14-15) ----
        if (tid < 256) {
            const int r = tid >> 7, u = tid & 127;
            const float gi = gl[r][u];
            const float gf = gl[r][HH + u];
            const float gG = gl[r][2 * HH + u];
            const float go = gl[r][3 * HH + u];
            c_reg = sigm(gf) * c_reg + sigm(gi) * tanh_f(gG);
            hx[cur ^ 1][r][u] = (_Float16)(sigm(go) * tanh_f(c_reg));
        }
        if (do_pre) hx[cur ^ 1][pr][HH + pk] = (_Float16)xpre;
        __syncthreads();
    }

    // ---- fused head: z = relu(h @ W1^T + b1); y = z @ W2^T + b2 ----
    // final h is in hx[0] (TT even). wave 0 -> row 0, wave 1 -> row 1.
    if (tid < 128) {
        const int r = tid >> 6, j = tid & 63;
        float z = b1v[j];
        const float* w1 = W1v + j * HH;
#pragma unroll 16
        for (int k = 0; k < HH; ++k)
            z = fmaf(w1[k], (float)hx[0][r][k], z);
        z = fmaxf(z, 0.f) * W2v[j];
#pragma unroll
        for (int off = 32; off; off >>= 1)
            z += __shfl_down(z, off, 64);
        if (j == 0) out[b0 + r] = z + b2v[0];
    }
}

extern "C" void kernel_launch(void* const* d_in, const int* in_sizes, int n_in,
                              void* d_out, int out_size, void* d_ws, size_t ws_size,
                              hipStream_t stream) {
    const float* x_seq = (const float*)d_in[0];
    const float* W_ih  = (const float*)d_in[1];
    const float* W_hh  = (const float*)d_in[2];
    const float* b_ih  = (const float*)d_in[3];
    const float* b_hh  = (const float*)d_in[4];
    const float* W1    = (const float*)d_in[5];
    const float* b1    = (const float*)d_in[6];
    const float* W2    = (const float*)d_in[7];
    const float* b2    = (const float*)d_in[8];
    float* out = (float*)d_out;

    lstm_fused_kernel<<<BB / 2, 1024, 0, stream>>>(
        x_seq, W_ih, W_hh, b_ih, b_hh, W1, b1, W2, b2, out);
}